// Round 11
// baseline (184.797 us; speedup 1.0000x reference)
//
#include <hip/hip_runtime.h>
#include <hip/hip_bf16.h>
#include <math.h>

typedef __attribute__((ext_vector_type(4))) float f32x4;
typedef __attribute__((ext_vector_type(8))) short bf16x8;

#define N_ROWS 8192
#define D 256
#define MSHIFT 16.0f
#define NKB 4
#define KRANGE (N_ROWS / NKB)     // 2048
#define NSTEP (KRANGE / 32)       // 64 (BK=32)

__device__ __forceinline__ unsigned short f2bf(float f) {
    unsigned int u = __float_as_uint(f);
    unsigned int r = u + 0x7FFFu + ((u >> 16) & 1u);
    return (unsigned short)(r >> 16);
}
__device__ __forceinline__ float bf2f(unsigned short h) {
    return __uint_as_float(((unsigned int)h) << 16);
}

__device__ __forceinline__ float breduce_sum256(float v, float* sb) {
#pragma unroll
    for (int off = 32; off; off >>= 1) v += __shfl_down(v, off);
    int wid = threadIdx.x >> 6;
    __syncthreads();
    if ((threadIdx.x & 63) == 0) sb[wid] = v;
    __syncthreads();
    return sb[0] + sb[1] + sb[2] + sb[3];
}

__device__ __forceinline__ void dma16(const void* g, void* l) {
    __builtin_amdgcn_global_load_lds(
        (const __attribute__((address_space(1))) unsigned int*)g,
        (__attribute__((address_space(3))) unsigned int*)l, 16, 0, 0);
}
// non-temporal variant: CPol NT bit (=2 on gfx94x/950) -> no L2/L3 allocate on miss.
// Streaming adj through NT keeps the 4 MB GT operand L2-resident (anti-thrash).
__device__ __forceinline__ void dma16nt(const void* g, void* l) {
    __builtin_amdgcn_global_load_lds(
        (const __attribute__((address_space(1))) unsigned int*)g,
        (__attribute__((address_space(3))) unsigned int*)l, 16, 0, 2);
}

__device__ __forceinline__ bf16x8 adj2bf(int4 a, int4 b) {
    bf16x8 r;
    r[0] = a.x ? (short)0x3F80 : (short)0;
    r[1] = a.y ? (short)0x3F80 : (short)0;
    r[2] = a.z ? (short)0x3F80 : (short)0;
    r[3] = a.w ? (short)0x3F80 : (short)0;
    r[4] = b.x ? (short)0x3F80 : (short)0;
    r[5] = b.y ? (short)0x3F80 : (short)0;
    r[6] = b.z ? (short)0x3F80 : (short)0;
    r[7] = b.w ? (short)0x3F80 : (short)0;
    return r;
}

// K1: M2 row k (f32) -> M2T hi/lo bf16 split [j][k]; v[k] = sum_j M2[k][j]*a2[j]
__global__ void k_M2v(const float* __restrict__ Wg, const float* __restrict__ Wa,
                      const float* __restrict__ aatt,
                      unsigned short* __restrict__ M2Thi, unsigned short* __restrict__ M2Tlo,
                      float* __restrict__ v) {
    __shared__ float sb[4];
    int k = blockIdx.x, t = threadIdx.x;
    float acc = 0.f;
#pragma unroll 8
    for (int m = 0; m < 255; ++m)
        acc += Wg[k * 255 + m] * Wa[(m + 1) * 256 + t];
    unsigned short hi = f2bf(acc);
    unsigned short lo = f2bf(acc - bf2f(hi));
    M2Thi[t * 256 + k] = hi;
    M2Tlo[t * 256 + k] = lo;
    if (k == 0) { M2Thi[t * 256 + 255] = 0; M2Tlo[t * 256 + 255] = 0; }
    float s = breduce_sum256(acc * aatt[256 + t], sb);
    if (t == 0) v[k] = s;
}

// K2: per-row logmap0 + c = logx.v + wexp; write wbf and w-scaled logx hi/lo bf16 (k-shifted)
__global__ void k_logw(const float* __restrict__ x, const float* __restrict__ v,
                       unsigned short* __restrict__ wbf,
                       unsigned short* __restrict__ Awhi, unsigned short* __restrict__ Awlo) {
    __shared__ float sb[4];
    int i0 = blockIdx.x * 8, t = threadIdx.x;
    float vv = (t >= 1) ? v[t - 1] : 0.f;
#pragma unroll
    for (int r = 0; r < 8; ++r) {
        float xv = x[(size_t)(i0 + r) * D + t];
        float yv = (t >= 1) ? xv : 0.f;
        float ss = breduce_sum256(yv * yv, sb);
        float x0 = x[(size_t)(i0 + r) * D];
        float coef = acoshf(fmaxf(x0, 1.f + 1e-7f)) / fmaxf(sqrtf(ss), 1e-15f);
        float lg = coef * yv;                 // logx[i][t]
        float c = breduce_sum256(lg * vv, sb);
        float w = expf(c - MSHIFT);
        if (t == r) wbf[i0 + r] = f2bf(w);
        float aw = w * lg;
        unsigned short hi = f2bf(aw);
        unsigned short lo = f2bf(aw - bf2f(hi));
        int kd = (t == 0) ? 255 : (t - 1);    // Aw[i][k] = w*logx[i][k+1], pad k=255 -> 0
        Awhi[(size_t)(i0 + r) * 256 + kd] = hi;
        Awlo[(size_t)(i0 + r) * 256 + kd] = lo;
    }
}

// K3: GT[c][i] = sum_k M2T[c][k] * Aw[i][k]  (3-term hi/lo MFMA). 512 thr, 64 i-cols/block.
__global__ void __launch_bounds__(512)
k_hGT(const unsigned short* __restrict__ M2Thi, const unsigned short* __restrict__ M2Tlo,
      const unsigned short* __restrict__ Awhi, const unsigned short* __restrict__ Awlo,
      unsigned short* __restrict__ GT) {
    __shared__ __align__(16) char ahi[32768], alo[32768], bhi[8192], blo[8192];
    const int tid = threadIdx.x;
    const int w = tid >> 6, l = tid & 63;
    const int lr = l & 15, lq = l >> 4;
    const int i0 = blockIdx.x * 64;
    const int gs = (l & 7) ^ (l >> 3);

    const unsigned short* srcAhi[4];
    const unsigned short* srcAlo[4];
#pragma unroll
    for (int i = 0; i < 4; ++i) {
        int rowA = (w * 4 + i) * 8 + (l >> 3);
        srcAhi[i] = M2Thi + rowA * 256 + gs * 8;
        srcAlo[i] = M2Tlo + rowA * 256 + gs * 8;
    }
    int rowB = w * 8 + (l >> 3);
    const unsigned short* srcBhi = Awhi + (size_t)(i0 + rowB) * 256 + gs * 8;
    const unsigned short* srcBlo = Awlo + (size_t)(i0 + rowB) * 256 + gs * 8;

    f32x4 zero4 = {0.f, 0.f, 0.f, 0.f};
    f32x4 acc[2][4];
#pragma unroll
    for (int m = 0; m < 2; ++m)
#pragma unroll
        for (int n = 0; n < 4; ++n) acc[m][n] = zero4;

    for (int t = 0; t < 4; ++t) {
        if (t) __syncthreads();
#pragma unroll
        for (int i = 0; i < 4; ++i) {
            dma16(srcAhi[i] + t * 64, ahi + (w * 4 + i) * 1024);
            dma16(srcAlo[i] + t * 64, alo + (w * 4 + i) * 1024);
        }
        dma16(srcBhi + t * 64, bhi + w * 1024);
        dma16(srcBlo + t * 64, blo + w * 1024);
        asm volatile("s_waitcnt vmcnt(0)" ::: "memory");
        __syncthreads();
#pragma unroll
        for (int ks = 0; ks < 2; ++ks) {
            const int g = ((ks * 4 + lq) ^ (lr & 7)) * 16;
            bf16x8 afh[2], afl[2];
#pragma unroll
            for (int m = 0; m < 2; ++m) {
                int row = w * 32 + m * 16 + lr;
                afh[m] = *(const bf16x8*)(ahi + row * 128 + g);
                afl[m] = *(const bf16x8*)(alo + row * 128 + g);
            }
#pragma unroll
            for (int n = 0; n < 4; ++n) {
                int rb = n * 16 + lr;
                bf16x8 bfh = *(const bf16x8*)(bhi + rb * 128 + g);
                bf16x8 bfl = *(const bf16x8*)(blo + rb * 128 + g);
#pragma unroll
                for (int m = 0; m < 2; ++m) {
                    acc[m][n] = __builtin_amdgcn_mfma_f32_16x16x32_bf16(afh[m], bfh, acc[m][n], 0, 0, 0);
                    acc[m][n] = __builtin_amdgcn_mfma_f32_16x16x32_bf16(afh[m], bfl, acc[m][n], 0, 0, 0);
                    acc[m][n] = __builtin_amdgcn_mfma_f32_16x16x32_bf16(afl[m], bfh, acc[m][n], 0, 0, 0);
                }
            }
        }
    }
#pragma unroll
    for (int m = 0; m < 2; ++m)
#pragma unroll
        for (int n = 0; n < 4; ++n)
#pragma unroll
            for (int vv = 0; vv < 4; ++vv) {
                int c = w * 32 + m * 16 + lq * 4 + vv;
                GT[(size_t)c * N_ROWS + i0 + n * 16 + lr] = f2bf(acc[m][n][vv]);
            }
}

// K4: masked GEMM. BM=64, BN=256, BK=32. 256 thr (4 waves, 2m x 2n), 2 blocks/CU.
// A (adj) staged with NON-TEMPORAL dma (no L2/L3 allocate) -> GT (4 MB) stays
// L2-resident instead of being thrash-evicted by the 256 MB adj stream.
// Triple-buffered, stage(t+1) before wait vmcnt(6), ONE s_barrier/step.
__global__ void __launch_bounds__(256, 2)
k_attadj(const int* __restrict__ adj, const unsigned short* __restrict__ GT,
         const unsigned short* __restrict__ wbf, float* __restrict__ part,
         float* __restrict__ rspart) {
    __shared__ __align__(16) char bufA[3 * 8192];    // 64 rows x 32 ints (128 B rows)
    __shared__ __align__(16) char bufB[3 * 16384];   // 256 cols x 32 bf16 (64 B rows)
    __shared__ __align__(16) char wlds[4096];        // KRANGE bf16 weights
    const int tid = threadIdx.x;
    const int kb = blockIdx.x & 3;
    const int rb = blockIdx.x >> 2;        // 0..127
    const int i0 = rb * 64;
    const int kbeg = kb * KRANGE;
    const int w = tid >> 6, l = tid & 63;
    const int lr = l & 15, lq = l >> 4;
    const int wm = w >> 1, wn = w & 1;     // 2 row-groups x 2 col-groups

    // A dma: inst a=w*2+i covers rows a*8..+7; lane: row8=l>>3, granule g=l&7;
    // LDS[row][g] = global[row][g ^ row8]  (16B granules, 8/row)
    const int row8 = l >> 3, gA = (l & 7) ^ row8;
    const int* srcA[2];
#pragma unroll
    for (int i = 0; i < 2; ++i) {
        int a = w * 2 + i;
        srcA[i] = adj + (size_t)(i0 + a * 8 + row8) * N_ROWS + kbeg + gA * 4;
    }
    // B dma: inst b=w*4+i covers cols b*16..+15; lane: col4=l>>2, g2=l&3;
    // LDS[col][g2] = global[col][g2 ^ (col&3)]  (16B granules, 4/row)
    const int col4 = l >> 2, gB = ((l & 3) ^ (col4 & 3)) * 8;
    const unsigned short* srcB[4];
#pragma unroll
    for (int i = 0; i < 4; ++i) {
        int b = w * 4 + i;
        srcB[i] = GT + (size_t)(b * 16 + col4) * N_ROWS + kbeg + gB;
    }

#define STAGE(T_, BI_) do {                                               \
        _Pragma("unroll")                                                 \
        for (int i_ = 0; i_ < 2; ++i_)                                    \
            dma16nt(srcA[i_] + (T_) * 32, bufA + (BI_) * 8192 + (w * 2 + i_) * 1024); \
        _Pragma("unroll")                                                 \
        for (int i_ = 0; i_ < 4; ++i_)                                    \
            dma16(srcB[i_] + (T_) * 32, bufB + (BI_) * 16384 + (w * 4 + i_) * 1024); \
    } while (0)

    f32x4 zero4 = {0.f, 0.f, 0.f, 0.f};
    f32x4 acc[2][8], acc_rs[2];
#pragma unroll
    for (int m = 0; m < 2; ++m) {
        acc_rs[m] = zero4;
#pragma unroll
        for (int n = 0; n < 8; ++n) acc[m][n] = zero4;
    }

    // prologue: stage step 0 + weight tile (7 dma outstanding per wave)
    STAGE(0, 0);
    dma16(wbf + kbeg + w * 512 + l * 8, wlds + w * 1024);

    int cb = 0;
    for (int t = 0; t < NSTEP; ++t) {
        int nb = (cb == 2) ? 0 : cb + 1;
        if (t + 1 < NSTEP) {
            STAGE(t + 1, nb);
            asm volatile("s_waitcnt vmcnt(6)" ::: "memory");   // drains STAGE(t) (+wlds at t=0)
        } else {
            asm volatile("s_waitcnt vmcnt(0)" ::: "memory");
        }
        __builtin_amdgcn_sched_barrier(0);
        __builtin_amdgcn_s_barrier();
        __builtin_amdgcn_sched_barrier(0);

        const char* bA = bufA + cb * 8192;
        const char* bB = bufB + cb * 16384;

        bf16x8 wf = {0, 0, 0, 0, 0, 0, 0, 0};
        if (lr == 0) wf = *(const bf16x8*)(wlds + t * 64 + lq * 16);

        bf16x8 af[2];
#pragma unroll
        for (int m = 0; m < 2; ++m) {
            int row = wm * 32 + m * 16 + lr;
            int4 u = *(const int4*)(bA + row * 128 + (((2 * lq) ^ (lr & 7)) << 4));
            int4 v2 = *(const int4*)(bA + row * 128 + (((2 * lq + 1) ^ (lr & 7)) << 4));
            af[m] = adj2bf(u, v2);
            acc_rs[m] = __builtin_amdgcn_mfma_f32_16x16x32_bf16(af[m], wf, acc_rs[m], 0, 0, 0);
        }
#pragma unroll
        for (int n = 0; n < 8; ++n) {
            int col = wn * 128 + n * 16 + lr;
            bf16x8 bf = *(const bf16x8*)(bB + col * 64 + ((lq ^ (lr & 3)) << 4));
#pragma unroll
            for (int m = 0; m < 2; ++m)
                acc[m][n] = __builtin_amdgcn_mfma_f32_16x16x32_bf16(af[m], bf, acc[m][n], 0, 0, 0);
        }
        cb = nb;
    }
#undef STAGE

    // rowsum (col 0 of acc_rs; wn duplicates -> wn==0 writes)
    if (wn == 0 && lr == 0) {
#pragma unroll
        for (int m = 0; m < 2; ++m)
#pragma unroll
            for (int vv = 0; vv < 4; ++vv)
                rspart[(size_t)kb * N_ROWS + i0 + wm * 32 + m * 16 + lq * 4 + vv] = acc_rs[m][vv];
    }

    // C write (layout: col=lane&15, row=(lane>>4)*4+reg); nontemporal
    float* pbase = part + (size_t)kb * N_ROWS * D;
#pragma unroll
    for (int m = 0; m < 2; ++m)
#pragma unroll
        for (int n = 0; n < 8; ++n) {
            int orow = i0 + wm * 32 + m * 16 + lq * 4;
            int ocol = wn * 128 + n * 16 + lr;
            float* op = pbase + (size_t)orow * D + ocol;
#pragma unroll
            for (int vv = 0; vv < 4; ++vv)
                __builtin_nontemporal_store(acc[m][n][vv], op + (size_t)vv * D);
        }
}

// K5: split-K reduce + epilogue (divide, elu, proj, logmap0, sigmoid, expmap0)
__global__ void k_final3(const float* __restrict__ part, const float* __restrict__ rspart,
                         float* __restrict__ out) {
    __shared__ float sb[4];
    int row = blockIdx.x, t = threadIdx.x;
    float raw = 0.f, rs = 0.f;
#pragma unroll
    for (int kbi = 0; kbi < NKB; ++kbi) {
        raw += __builtin_nontemporal_load(&part[((size_t)kbi * N_ROWS + row) * D + t]);
        rs += rspart[(size_t)kbi * N_ROWS + row];
    }
    float hp = raw / rs;
    float ey = 0.f;
    if (t >= 1) ey = (hp > 0.f) ? hp : expm1f(hp);
    float ss = breduce_sum256(ey * ey, sb);
    float x0 = sqrtf(1.f + ss);
    float th = fmaxf(x0, 1.f + 1e-7f);
    float al = acoshf(th);
    float yn = fmaxf(sqrtf(ss), 1e-15f);
    float u = (t >= 1) ? (al * ey / yn) : 0.f;
    float s = 1.f / (1.f + expf(-u));
    float s2 = (t >= 1) ? s * s : 0.f;
    float ssn = breduce_sum256(s2, sb);
    float xn = fmaxf(sqrtf(ssn), 1e-15f);
    float sh = sinhf(xn);
    float yf = (t >= 1) ? (sh * s / xn) : 0.f;
    float sy = breduce_sum256(yf * yf, sb);
    float res = (t == 0) ? sqrtf(1.f + sy) : yf;
    out[(size_t)row * D + t] = res;
}

extern "C" void kernel_launch(void* const* d_in, const int* in_sizes, int n_in,
                              void* d_out, int out_size, void* d_ws, size_t ws_size,
                              hipStream_t stream) {
    const float* x    = (const float*)d_in[0];
    const int*   adj  = (const int*)d_in[1];
    const float* Wg   = (const float*)d_in[3];
    const float* Wa   = (const float*)d_in[4];
    const float* aatt = (const float*)d_in[5];
    float* out = (float*)d_out;

    char* wsb = (char*)d_ws;
    unsigned short* M2Thi  = (unsigned short*)(wsb);              // 128 KB
    unsigned short* M2Tlo  = (unsigned short*)(wsb + 0x0020000);  // 128 KB
    float*          v      = (float*)(wsb + 0x0040000);           // 1 KB
    unsigned short* wbf    = (unsigned short*)(wsb + 0x0048000);  // 16 KB
    unsigned short* Awhi   = (unsigned short*)(wsb + 0x0100000);  // 4 MB
    unsigned short* Awlo   = (unsigned short*)(wsb + 0x0500000);  // 4 MB
    unsigned short* GT     = (unsigned short*)(wsb + 0x0900000);  // 4 MB
    float*          rspart = (float*)(wsb + 0x0D00000);           // 128 KB
    float*          part   = (float*)(wsb + 0x1000000);           // 32 MB

    k_M2v<<<255, 256, 0, stream>>>(Wg, Wa, aatt, M2Thi, M2Tlo, v);
    k_logw<<<N_ROWS / 8, 256, 0, stream>>>(x, v, wbf, Awhi, Awlo);
    k_hGT<<<N_ROWS / 64, 512, 0, stream>>>(M2Thi, M2Tlo, Awhi, Awlo, GT);
    k_attadj<<<128 * NKB, 256, 0, stream>>>(adj, GT, wbf, part, rspart);
    k_final3<<<N_ROWS, 256, 0, stream>>>(part, rspart, out);
}

// Round 12
// 156.554 us; speedup vs baseline: 1.1804x; 1.1804x over previous
//
#include <hip/hip_runtime.h>
#include <hip/hip_bf16.h>
#include <math.h>

typedef __attribute__((ext_vector_type(4))) float f32x4;
typedef __attribute__((ext_vector_type(8))) short bf16x8;

#define N_ROWS 8192
#define D 256
#define MSHIFT 16.0f
#define NKB 8
#define KRANGE (N_ROWS / NKB)     // 1024
#define NSTEP (KRANGE / 32)       // 32 (BK=32)

__device__ __forceinline__ unsigned short f2bf(float f) {
    unsigned int u = __float_as_uint(f);
    unsigned int r = u + 0x7FFFu + ((u >> 16) & 1u);
    return (unsigned short)(r >> 16);
}
__device__ __forceinline__ float bf2f(unsigned short h) {
    return __uint_as_float(((unsigned int)h) << 16);
}

__device__ __forceinline__ float breduce_sum256(float v, float* sb) {
#pragma unroll
    for (int off = 32; off; off >>= 1) v += __shfl_down(v, off);
    int wid = threadIdx.x >> 6;
    __syncthreads();
    if ((threadIdx.x & 63) == 0) sb[wid] = v;
    __syncthreads();
    return sb[0] + sb[1] + sb[2] + sb[3];
}

__device__ __forceinline__ void dma16(const void* g, void* l) {
    __builtin_amdgcn_global_load_lds(
        (const __attribute__((address_space(1))) unsigned int*)g,
        (__attribute__((address_space(3))) unsigned int*)l, 16, 0, 0);
}

__device__ __forceinline__ bf16x8 adj2bf(int4 a, int4 b) {
    bf16x8 r;
    r[0] = a.x ? (short)0x3F80 : (short)0;
    r[1] = a.y ? (short)0x3F80 : (short)0;
    r[2] = a.z ? (short)0x3F80 : (short)0;
    r[3] = a.w ? (short)0x3F80 : (short)0;
    r[4] = b.x ? (short)0x3F80 : (short)0;
    r[5] = b.y ? (short)0x3F80 : (short)0;
    r[6] = b.z ? (short)0x3F80 : (short)0;
    r[7] = b.w ? (short)0x3F80 : (short)0;
    return r;
}

// K1: M2 row k (f32) -> M2T hi/lo bf16 split [j][k]; v[k] = sum_j M2[k][j]*a2[j]
__global__ void k_M2v(const float* __restrict__ Wg, const float* __restrict__ Wa,
                      const float* __restrict__ aatt,
                      unsigned short* __restrict__ M2Thi, unsigned short* __restrict__ M2Tlo,
                      float* __restrict__ v) {
    __shared__ float sb[4];
    int k = blockIdx.x, t = threadIdx.x;
    float acc = 0.f;
#pragma unroll 8
    for (int m = 0; m < 255; ++m)
        acc += Wg[k * 255 + m] * Wa[(m + 1) * 256 + t];
    unsigned short hi = f2bf(acc);
    unsigned short lo = f2bf(acc - bf2f(hi));
    M2Thi[t * 256 + k] = hi;
    M2Tlo[t * 256 + k] = lo;
    if (k == 0) { M2Thi[t * 256 + 255] = 0; M2Tlo[t * 256 + 255] = 0; }
    float s = breduce_sum256(acc * aatt[256 + t], sb);
    if (t == 0) v[k] = s;
}

// K2: per-row logmap0 + c = logx.v + wexp; write wbf and w-scaled logx hi/lo bf16 (k-shifted)
__global__ void k_logw(const float* __restrict__ x, const float* __restrict__ v,
                       unsigned short* __restrict__ wbf,
                       unsigned short* __restrict__ Awhi, unsigned short* __restrict__ Awlo) {
    __shared__ float sb[4];
    int i0 = blockIdx.x * 8, t = threadIdx.x;
    float vv = (t >= 1) ? v[t - 1] : 0.f;
#pragma unroll
    for (int r = 0; r < 8; ++r) {
        float xv = x[(size_t)(i0 + r) * D + t];
        float yv = (t >= 1) ? xv : 0.f;
        float ss = breduce_sum256(yv * yv, sb);
        float x0 = x[(size_t)(i0 + r) * D];
        float coef = acoshf(fmaxf(x0, 1.f + 1e-7f)) / fmaxf(sqrtf(ss), 1e-15f);
        float lg = coef * yv;                 // logx[i][t]
        float c = breduce_sum256(lg * vv, sb);
        float w = expf(c - MSHIFT);
        if (t == r) wbf[i0 + r] = f2bf(w);
        float aw = w * lg;
        unsigned short hi = f2bf(aw);
        unsigned short lo = f2bf(aw - bf2f(hi));
        int kd = (t == 0) ? 255 : (t - 1);    // Aw[i][k] = w*logx[i][k+1], pad k=255 -> 0
        Awhi[(size_t)(i0 + r) * 256 + kd] = hi;
        Awlo[(size_t)(i0 + r) * 256 + kd] = lo;
    }
}

// K3: GT[c][i] = sum_k M2T[c][k] * Aw[i][k]  (3-term hi/lo MFMA). 512 thr, 64 i-cols/block.
__global__ void __launch_bounds__(512)
k_hGT(const unsigned short* __restrict__ M2Thi, const unsigned short* __restrict__ M2Tlo,
      const unsigned short* __restrict__ Awhi, const unsigned short* __restrict__ Awlo,
      unsigned short* __restrict__ GT) {
    __shared__ __align__(16) char ahi[32768], alo[32768], bhi[8192], blo[8192];
    const int tid = threadIdx.x;
    const int w = tid >> 6, l = tid & 63;
    const int lr = l & 15, lq = l >> 4;
    const int i0 = blockIdx.x * 64;
    const int gs = (l & 7) ^ (l >> 3);

    const unsigned short* srcAhi[4];
    const unsigned short* srcAlo[4];
#pragma unroll
    for (int i = 0; i < 4; ++i) {
        int rowA = (w * 4 + i) * 8 + (l >> 3);
        srcAhi[i] = M2Thi + rowA * 256 + gs * 8;
        srcAlo[i] = M2Tlo + rowA * 256 + gs * 8;
    }
    int rowB = w * 8 + (l >> 3);
    const unsigned short* srcBhi = Awhi + (size_t)(i0 + rowB) * 256 + gs * 8;
    const unsigned short* srcBlo = Awlo + (size_t)(i0 + rowB) * 256 + gs * 8;

    f32x4 zero4 = {0.f, 0.f, 0.f, 0.f};
    f32x4 acc[2][4];
#pragma unroll
    for (int m = 0; m < 2; ++m)
#pragma unroll
        for (int n = 0; n < 4; ++n) acc[m][n] = zero4;

    for (int t = 0; t < 4; ++t) {
        if (t) __syncthreads();
#pragma unroll
        for (int i = 0; i < 4; ++i) {
            dma16(srcAhi[i] + t * 64, ahi + (w * 4 + i) * 1024);
            dma16(srcAlo[i] + t * 64, alo + (w * 4 + i) * 1024);
        }
        dma16(srcBhi + t * 64, bhi + w * 1024);
        dma16(srcBlo + t * 64, blo + w * 1024);
        asm volatile("s_waitcnt vmcnt(0)" ::: "memory");
        __syncthreads();
#pragma unroll
        for (int ks = 0; ks < 2; ++ks) {
            const int g = ((ks * 4 + lq) ^ (lr & 7)) * 16;
            bf16x8 afh[2], afl[2];
#pragma unroll
            for (int m = 0; m < 2; ++m) {
                int row = w * 32 + m * 16 + lr;
                afh[m] = *(const bf16x8*)(ahi + row * 128 + g);
                afl[m] = *(const bf16x8*)(alo + row * 128 + g);
            }
#pragma unroll
            for (int n = 0; n < 4; ++n) {
                int rb = n * 16 + lr;
                bf16x8 bfh = *(const bf16x8*)(bhi + rb * 128 + g);
                bf16x8 bfl = *(const bf16x8*)(blo + rb * 128 + g);
#pragma unroll
                for (int m = 0; m < 2; ++m) {
                    acc[m][n] = __builtin_amdgcn_mfma_f32_16x16x32_bf16(afh[m], bfh, acc[m][n], 0, 0, 0);
                    acc[m][n] = __builtin_amdgcn_mfma_f32_16x16x32_bf16(afh[m], bfl, acc[m][n], 0, 0, 0);
                    acc[m][n] = __builtin_amdgcn_mfma_f32_16x16x32_bf16(afl[m], bfh, acc[m][n], 0, 0, 0);
                }
            }
        }
    }
#pragma unroll
    for (int m = 0; m < 2; ++m)
#pragma unroll
        for (int n = 0; n < 4; ++n)
#pragma unroll
            for (int vv = 0; vv < 4; ++vv) {
                int c = w * 32 + m * 16 + lq * 4 + vv;
                GT[(size_t)c * N_ROWS + i0 + n * 16 + lr] = f2bf(acc[m][n][vv]);
            }
}

// K4: masked GEMM. BM=256, BN=256, BK=32. 512 thr (8 waves, 4m x 2n), 1 block/CU.
// Staged-bytes-minimal geometry: A(adj) 256 MB read once, B(GT) re-staged only
// 32x (8192/256) = 128 MB, part 64 MB. Triple-buffered dma16, stage(t+1) before
// wait vmcnt(6), one s_barrier/step. kb=blockIdx&7 -> XCD-pinned 512 KB GT slice.
__global__ void __launch_bounds__(512, 2)
k_attadj(const int* __restrict__ adj, const unsigned short* __restrict__ GT,
         const unsigned short* __restrict__ wbf, float* __restrict__ part,
         float* __restrict__ rspart) {
    __shared__ __align__(16) char bufA[3 * 32768];   // 256 rows x 32 ints (128 B rows)
    __shared__ __align__(16) char bufB[3 * 16384];   // 256 cols x 32 bf16 (64 B rows)
    __shared__ __align__(16) char wlds[2048];        // KRANGE bf16 weights
    const int tid = threadIdx.x;
    const int kb = blockIdx.x & 7;         // = XCD id under b%8 dispatch -> pinned GT slice
    const int rb = blockIdx.x >> 3;        // 0..31
    const int i0 = rb * 256;
    const int kbeg = kb * KRANGE;
    const int w = tid >> 6, l = tid & 63;
    const int lr = l & 15, lq = l >> 4;
    const int wm = w >> 1, wn = w & 1;     // 4 row-groups x 2 col-groups

    // A dma: 32 insts (4/wave): inst a covers rows a*8..+7; lane: row8=l>>3,
    // granule g=l&7 (16B=4 ints); LDS[row][g] = global[row][g ^ (row&7)]
    const int row8 = l >> 3, gA = (l & 7) ^ row8;
    const int* srcA[4];
#pragma unroll
    for (int i = 0; i < 4; ++i) {
        int a = w * 4 + i;
        srcA[i] = adj + (size_t)(i0 + a * 8 + row8) * N_ROWS + kbeg + gA * 4;
    }
    // B dma: 16 insts (2/wave): inst b covers cols b*16..+15; lane: col4=l>>2,
    // g2 (16B=8 bf16); LDS[col][g2] = global[col][g2 ^ (col&3)]
    const int col4 = l >> 2, gB = ((l & 3) ^ (col4 & 3)) * 8;
    const unsigned short* srcB[2];
#pragma unroll
    for (int i = 0; i < 2; ++i) {
        int b = w * 2 + i;
        srcB[i] = GT + (size_t)(b * 16 + col4) * N_ROWS + kbeg + gB;
    }

#define STAGE(T_, BI_) do {                                                \
        _Pragma("unroll")                                                  \
        for (int i_ = 0; i_ < 4; ++i_)                                     \
            dma16(srcA[i_] + (T_) * 32, bufA + (BI_) * 32768 + (w * 4 + i_) * 1024); \
        _Pragma("unroll")                                                  \
        for (int i_ = 0; i_ < 2; ++i_)                                     \
            dma16(srcB[i_] + (T_) * 32, bufB + (BI_) * 16384 + (w * 2 + i_) * 1024); \
    } while (0)

    f32x4 zero4 = {0.f, 0.f, 0.f, 0.f};
    f32x4 acc[4][8], acc_rs[4];
#pragma unroll
    for (int m = 0; m < 4; ++m) {
        acc_rs[m] = zero4;
#pragma unroll
        for (int n = 0; n < 8; ++n) acc[m][n] = zero4;
    }

    // prologue: stage step 0 + weight tile (6-7 dma outstanding per wave)
    STAGE(0, 0);
    if (w < 2) dma16(wbf + kbeg + w * 512 + l * 8, wlds + w * 1024);

    int cb = 0;
    for (int t = 0; t < NSTEP; ++t) {
        int nb = (cb == 2) ? 0 : cb + 1;
        if (t + 1 < NSTEP) {
            STAGE(t + 1, nb);
            asm volatile("s_waitcnt vmcnt(6)" ::: "memory");   // drains STAGE(t) (+wlds at t=0)
        } else {
            asm volatile("s_waitcnt vmcnt(0)" ::: "memory");
        }
        __builtin_amdgcn_sched_barrier(0);
        __builtin_amdgcn_s_barrier();
        __builtin_amdgcn_sched_barrier(0);

        const char* bA = bufA + cb * 32768;
        const char* bB = bufB + cb * 16384;

        bf16x8 wf = {0, 0, 0, 0, 0, 0, 0, 0};
        if (lr == 0) wf = *(const bf16x8*)(wlds + t * 64 + lq * 16);

        bf16x8 af[4];
#pragma unroll
        for (int m = 0; m < 4; ++m) {
            int row = wm * 64 + m * 16 + lr;
            int4 u  = *(const int4*)(bA + row * 128 + (((2 * lq) ^ (lr & 7)) << 4));
            int4 v2 = *(const int4*)(bA + row * 128 + (((2 * lq + 1) ^ (lr & 7)) << 4));
            af[m] = adj2bf(u, v2);
            acc_rs[m] = __builtin_amdgcn_mfma_f32_16x16x32_bf16(af[m], wf, acc_rs[m], 0, 0, 0);
        }
#pragma unroll
        for (int n = 0; n < 8; ++n) {
            int col = wn * 128 + n * 16 + lr;
            bf16x8 bf = *(const bf16x8*)(bB + col * 64 + ((lq ^ (lr & 3)) << 4));
#pragma unroll
            for (int m = 0; m < 4; ++m)
                acc[m][n] = __builtin_amdgcn_mfma_f32_16x16x32_bf16(af[m], bf, acc[m][n], 0, 0, 0);
        }
        cb = nb;
    }
#undef STAGE

    // rowsum (col 0 of acc_rs; wn duplicates -> wn==0 writes)
    if (wn == 0 && lr == 0) {
#pragma unroll
        for (int m = 0; m < 4; ++m)
#pragma unroll
            for (int vv = 0; vv < 4; ++vv)
                rspart[(size_t)kb * N_ROWS + i0 + wm * 64 + m * 16 + lq * 4 + vv] = acc_rs[m][vv];
    }

    // C write (layout: col=lane&15, row=(lane>>4)*4+reg); nontemporal
    float* pbase = part + (size_t)kb * N_ROWS * D;
#pragma unroll
    for (int m = 0; m < 4; ++m)
#pragma unroll
        for (int n = 0; n < 8; ++n) {
            int orow = i0 + wm * 64 + m * 16 + lq * 4;
            int ocol = wn * 128 + n * 16 + lr;
            float* op = pbase + (size_t)orow * D + ocol;
#pragma unroll
            for (int vv = 0; vv < 4; ++vv)
                __builtin_nontemporal_store(acc[m][n][vv], op + (size_t)vv * D);
        }
}

// K5: split-K reduce + epilogue (divide, elu, proj, logmap0, sigmoid, expmap0)
__global__ void k_final3(const float* __restrict__ part, const float* __restrict__ rspart,
                         float* __restrict__ out) {
    __shared__ float sb[4];
    int row = blockIdx.x, t = threadIdx.x;
    float raw = 0.f, rs = 0.f;
#pragma unroll
    for (int kbi = 0; kbi < NKB; ++kbi) {
        raw += __builtin_nontemporal_load(&part[((size_t)kbi * N_ROWS + row) * D + t]);
        rs += rspart[(size_t)kbi * N_ROWS + row];
    }
    float hp = raw / rs;
    float ey = 0.f;
    if (t >= 1) ey = (hp > 0.f) ? hp : expm1f(hp);
    float ss = breduce_sum256(ey * ey, sb);
    float x0 = sqrtf(1.f + ss);
    float th = fmaxf(x0, 1.f + 1e-7f);
    float al = acoshf(th);
    float yn = fmaxf(sqrtf(ss), 1e-15f);
    float u = (t >= 1) ? (al * ey / yn) : 0.f;
    float s = 1.f / (1.f + expf(-u));
    float s2 = (t >= 1) ? s * s : 0.f;
    float ssn = breduce_sum256(s2, sb);
    float xn = fmaxf(sqrtf(ssn), 1e-15f);
    float sh = sinhf(xn);
    float yf = (t >= 1) ? (sh * s / xn) : 0.f;
    float sy = breduce_sum256(yf * yf, sb);
    float res = (t == 0) ? sqrtf(1.f + sy) : yf;
    out[(size_t)row * D + t] = res;
}

extern "C" void kernel_launch(void* const* d_in, const int* in_sizes, int n_in,
                              void* d_out, int out_size, void* d_ws, size_t ws_size,
                              hipStream_t stream) {
    const float* x    = (const float*)d_in[0];
    const int*   adj  = (const int*)d_in[1];
    const float* Wg   = (const float*)d_in[3];
    const float* Wa   = (const float*)d_in[4];
    const float* aatt = (const float*)d_in[5];
    float* out = (float*)d_out;

    char* wsb = (char*)d_ws;
    unsigned short* M2Thi  = (unsigned short*)(wsb);              // 128 KB
    unsigned short* M2Tlo  = (unsigned short*)(wsb + 0x0020000);  // 128 KB
    float*          v      = (float*)(wsb + 0x0040000);           // 1 KB
    unsigned short* wbf    = (unsigned short*)(wsb + 0x0048000);  // 16 KB
    unsigned short* Awhi   = (unsigned short*)(wsb + 0x0100000);  // 4 MB
    unsigned short* Awlo   = (unsigned short*)(wsb + 0x0500000);  // 4 MB
    unsigned short* GT     = (unsigned short*)(wsb + 0x0900000);  // 4 MB
    float*          rspart = (float*)(wsb + 0x0D00000);           // 256 KB
    float*          part   = (float*)(wsb + 0x1000000);           // 64 MB (NKB x 8 MB)

    k_M2v<<<255, 256, 0, stream>>>(Wg, Wa, aatt, M2Thi, M2Tlo, v);
    k_logw<<<N_ROWS / 8, 256, 0, stream>>>(x, v, wbf, Awhi, Awlo);
    k_hGT<<<N_ROWS / 64, 512, 0, stream>>>(M2Thi, M2Tlo, Awhi, Awlo, GT);
    k_attadj<<<32 * NKB, 512, 0, stream>>>(adj, GT, wbf, part, rspart);
    k_final3<<<N_ROWS, 256, 0, stream>>>(part, rspart, out);
}